// Round 2
// baseline (7556.157 us; speedup 1.0000x reference)
//
#include <hip/hip_runtime.h>

// Problem constants
#define M_TOK 32000   // B*T = 16*2000 tokens
#define DIM   512     // feature dim
#define KCB   1024    // codebook size
#define NQ    8       // quantizer stages
// GEMM tiling
#define BM 128
#define BN 128
#define NSPLIT 4      // codebook chunks per token-block (grid = 250*4)
#define CHUNK 256     // KCB / NSPLIT
#define BKC 16
#define LDSPAD 132    // row length: (132*4B)%128B != 0 -> writes 2-way max

__device__ __forceinline__ float wave_reduce_sum(float v) {
#pragma unroll
  for (int off = 32; off > 0; off >>= 1) v += __shfl_xor(v, off, 64);
  return v;
}

// Monotone float->uint mapping: a<b (float) <=> fenc(a)<fenc(b) (uint)
__device__ __forceinline__ unsigned int fenc(float f) {
  unsigned int u = __float_as_uint(f);
  return (u & 0x80000000u) ? ~u : (u | 0x80000000u);
}

// Precompute per-stage codebook norms e2[8*1024], per-token ||x||^2 r2[32000],
// and zero the loss accumulator. One wave per row.
__global__ __launch_bounds__(256) void rvq_init_kernel(
    const float* __restrict__ x, const float* __restrict__ cb,
    float* __restrict__ e2, float* __restrict__ r2, float* __restrict__ lossCell) {
  if (blockIdx.x == 0 && threadIdx.x == 0) *lossCell = 0.f;
  int row = blockIdx.x * 4 + (threadIdx.x >> 6);
  int lane = threadIdx.x & 63;
  const float* src;
  float* dst;
  if (row < NQ * KCB) {
    src = cb + (size_t)row * DIM;
    dst = e2 + row;
  } else {
    int t = row - NQ * KCB;
    if (t >= M_TOK) return;
    src = x + (size_t)t * DIM;
    dst = r2 + t;
  }
  const float4* s4 = (const float4*)src;
  float s = 0.f;
  float4 v = s4[lane];
  s += v.x * v.x + v.y * v.y + v.z * v.z + v.w * v.w;
  v = s4[lane + 64];
  s += v.x * v.x + v.y * v.y + v.z * v.z + v.w * v.w;
  s = wave_reduce_sum(s);
  if (lane == 0) *dst = s;
}

// Argmin over a 256-codeword chunk for 128 tokens; fold into global packed
// (dist,idx) key via atomicMin. Lexicographic min == first-index ties.
__global__ __launch_bounds__(256, 4) void rvq_argmin_kernel(
    const float* __restrict__ rin,   // [32000][512] current residual
    const float* __restrict__ cb,    // [1024][512] this stage's codebook
    const float* __restrict__ e2,    // [1024]
    const float* __restrict__ r2in,  // [32000]
    unsigned long long* __restrict__ keys) {  // [32000], pre-set to ~0
  __shared__ float As[BKC][LDSPAD];
  __shared__ float Bs[BKC][LDSPAD];
  __shared__ float e2s[CHUNK];

  const int tid = threadIdx.x;
  const int tx = tid & 15, ty = tid >> 4;
  const int mblk = blockIdx.x >> 2;   // 0..249
  const int nsp  = blockIdx.x & 3;    // 0..3
  const int m0 = mblk * BM;
  const int c0 = nsp * CHUNK;

  e2s[tid] = e2[c0 + tid];

  float r2reg[8];
#pragma unroll
  for (int i = 0; i < 8; ++i)
    r2reg[i] = r2in[m0 + (i >> 2) * 64 + ty * 4 + (i & 3)];

  float minv[8];
  int mini[8];
#pragma unroll
  for (int i = 0; i < 8; ++i) { minv[i] = 3.4e38f; mini[i] = 0; }

  for (int nc = 0; nc < CHUNK / BN; ++nc) {
    float acc[8][8];
#pragma unroll
    for (int i = 0; i < 8; ++i)
#pragma unroll
      for (int j = 0; j < 8; ++j) acc[i][j] = 0.f;

    for (int kc = 0; kc < DIM; kc += BKC) {
      __syncthreads();  // protect LDS from previous iteration's readers
#pragma unroll
      for (int t = 0; t < 2; ++t) {
        int f4 = tid + t * 256;          // 512 float4 slots per tile
        int r = f4 >> 2, kg = f4 & 3;    // row (token/codeword), k-group of 4
        float4 a = *(const float4*)(rin + (size_t)(m0 + r) * DIM + kc + kg * 4);
        As[kg * 4 + 0][r] = a.x; As[kg * 4 + 1][r] = a.y;
        As[kg * 4 + 2][r] = a.z; As[kg * 4 + 3][r] = a.w;
        float4 b = *(const float4*)(cb + (size_t)(c0 + nc * BN + r) * DIM + kc + kg * 4);
        Bs[kg * 4 + 0][r] = b.x; Bs[kg * 4 + 1][r] = b.y;
        Bs[kg * 4 + 2][r] = b.z; Bs[kg * 4 + 3][r] = b.w;
      }
      __syncthreads();
#pragma unroll
      for (int kd = 0; kd < BKC; ++kd) {
        // 16 B-stride fragments: banks tx*4..tx*4+3 -> 2-way alias (free)
        float4 a0 = *(const float4*)&As[kd][ty * 4];
        float4 a1 = *(const float4*)&As[kd][64 + ty * 4];
        float4 b0 = *(const float4*)&Bs[kd][tx * 4];
        float4 b1 = *(const float4*)&Bs[kd][64 + tx * 4];
        float av[8] = {a0.x, a0.y, a0.z, a0.w, a1.x, a1.y, a1.z, a1.w};
        float bv[8] = {b0.x, b0.y, b0.z, b0.w, b1.x, b1.y, b1.z, b1.w};
#pragma unroll
        for (int i = 0; i < 8; ++i)
#pragma unroll
          for (int j = 0; j < 8; ++j) acc[i][j] = fmaf(av[i], bv[j], acc[i][j]);
      }
    }
    // fold this N-chunk into the running argmin (reference: (r2 - 2*dot) + e2)
#pragma unroll
    for (int i = 0; i < 8; ++i) {
#pragma unroll
      for (int j = 0; j < 8; ++j) {
        int cl = nc * BN + (j >> 2) * 64 + tx * 4 + (j & 3);  // ascending in j
        float d = (r2reg[i] - 2.f * acc[i][j]) + e2s[cl];
        if (d < minv[i]) { minv[i] = d; mini[i] = c0 + cl; }
      }
    }
  }

  // Reduce across the 16 tx lanes (contiguous in-wave group), then atomicMin.
#pragma unroll
  for (int i = 0; i < 8; ++i) {
    float v = minv[i];
    int ix = mini[i];
#pragma unroll
    for (int off = 8; off; off >>= 1) {
      float ov = __shfl_xor(v, off, 16);
      int oi = __shfl_xor(ix, off, 16);
      if (ov < v || (ov == v && oi < ix)) { v = ov; ix = oi; }
    }
    if (tx == 0) {
      int row = (i >> 2) * 64 + ty * 4 + (i & 3);
      unsigned long long key = ((unsigned long long)fenc(v) << 32) | (unsigned)ix;
      atomicMin(&keys[m0 + row], key);
    }
  }
}

// Per-token epilogue: decode winner, gather codeword, straight-through
// residual update (exact reference rounding), next ||r||^2, loss partial.
__global__ __launch_bounds__(256) void rvq_update_kernel(
    const float* __restrict__ rin, const float* __restrict__ cb,
    const unsigned long long* __restrict__ keys,
    float* __restrict__ rout, float* __restrict__ r2out,
    float* __restrict__ idx_out, float* __restrict__ lossCell) {
  const int tok = blockIdx.x * 4 + (threadIdx.x >> 6);
  const int lane = threadIdx.x & 63;
  if (tok >= M_TOK) return;
  const unsigned idx = (unsigned)(keys[tok] & 0xffffffffu);
  if (lane == 0) idx_out[tok] = (float)idx;
  const float4* rrow = (const float4*)(rin + (size_t)tok * DIM);
  const float4* crow = (const float4*)(cb + (size_t)idx * DIM);
  float4* orow = (float4*)(rout + (size_t)tok * DIM);
  float ssq_t = 0.f, ssq_r = 0.f;
#pragma unroll
  for (int c4 = 0; c4 < 2; ++c4) {
    int c = lane + c4 * 64;
    float4 a = rrow[c], q = crow[c];
    // t = q - r; qst = r + t; r_new = r - qst; loss += t^2
    float4 t = make_float4(q.x - a.x, q.y - a.y, q.z - a.z, q.w - a.w);
    float4 qst = make_float4(a.x + t.x, a.y + t.y, a.z + t.z, a.w + t.w);
    float4 rn = make_float4(a.x - qst.x, a.y - qst.y, a.z - qst.z, a.w - qst.w);
    orow[c] = rn;
    ssq_t += t.x * t.x + t.y * t.y + t.z * t.z + t.w * t.w;
    ssq_r += rn.x * rn.x + rn.y * rn.y + rn.z * rn.z + rn.w * rn.w;
  }
  float tot_t = wave_reduce_sum(ssq_t);
  float tot_r = wave_reduce_sum(ssq_r);
  if (lane == 0) {
    r2out[tok] = tot_r;
    atomicAdd(lossCell, tot_t);
  }
}

// out currently holds r_8; replace with x - r_8. Also emit final loss.
__global__ __launch_bounds__(256) void rvq_finalize_kernel(
    const float* __restrict__ x, float* __restrict__ out,
    const float* __restrict__ lossCell, float* __restrict__ loss_out) {
  size_t i = (size_t)blockIdx.x * 256 + threadIdx.x;
  const size_t n4 = (size_t)M_TOK * DIM / 4;  // 4,096,000
  if (i < n4) {
    const float4* x4 = (const float4*)x;
    float4* o4 = (float4*)out;
    float4 a = x4[i], r = o4[i];
    o4[i] = make_float4(a.x - r.x, a.y - r.y, a.z - r.z, a.w - r.w);
  }
  if (blockIdx.x == 0 && threadIdx.x == 0) {
    // mean over stages of 1.25*mean_elem(t^2): scale = 1.25 / (8 * 16384000)
    *loss_out = *lossCell * (1.25f / 131072000.f);
  }
}

extern "C" void kernel_launch(void* const* d_in, const int* in_sizes, int n_in,
                              void* d_out, int out_size, void* d_ws, size_t ws_size,
                              hipStream_t stream) {
  const float* x = (const float*)d_in[0];        // [16,2000,512]
  const float* cb = (const float*)d_in[1];       // [8,1024,512]
  float* out = (float*)d_out;                    // quantized region doubles as residual buffer
  float* idx_out = out + (size_t)M_TOK * DIM;    // [8][32000] indices as float
  float* loss_out = idx_out + (size_t)NQ * M_TOK;  // scalar
  // workspace: keys[32000] (u64) | e2[8192] | r2[32000] | lossCell[1]
  unsigned long long* keys = (unsigned long long*)d_ws;
  float* e2 = (float*)(keys + M_TOK);
  float* r2 = e2 + NQ * KCB;
  float* lossCell = r2 + M_TOK;

  {
    int rows = NQ * KCB + M_TOK;  // 40192
    rvq_init_kernel<<<(rows + 3) / 4, 256, 0, stream>>>(x, cb, e2, r2, lossCell);
  }
  float* resbuf = out;
  for (int s = 0; s < NQ; ++s) {
    const float* rin = (s == 0) ? x : resbuf;
    const float* cbs = cb + (size_t)s * KCB * DIM;
    hipMemsetAsync(keys, 0xFF, (size_t)M_TOK * sizeof(unsigned long long), stream);
    rvq_argmin_kernel<<<(M_TOK / BM) * NSPLIT, 256, 0, stream>>>(
        rin, cbs, e2 + s * KCB, r2, keys);
    rvq_update_kernel<<<M_TOK / 4, 256, 0, stream>>>(
        rin, cbs, keys, resbuf, r2, idx_out + (size_t)s * M_TOK, lossCell);
  }
  rvq_finalize_kernel<<<(M_TOK * DIM / 4 + 255) / 256, 256, 0, stream>>>(
      x, out, lossCell, loss_out);
}

// Round 3
// 1213.189 us; speedup vs baseline: 6.2283x; 6.2283x over previous
//
#include <hip/hip_runtime.h>

// Problem constants
#define M_TOK 32000   // B*T tokens
#define DIM   512     // feature dim
#define KCB   1024    // codebook size
#define NQ    8       // quantizer stages
// GEMM tiling
#define BM 64
#define BN 256
#define BK 32
#define KSTEPS (DIM / BK)   // 16

typedef _Float16 f16x8 __attribute__((ext_vector_type(8)));
typedef _Float16 f16x4 __attribute__((ext_vector_type(4)));
typedef float f32x4 __attribute__((ext_vector_type(4)));

__device__ __forceinline__ float wave_reduce_sum(float v) {
#pragma unroll
  for (int off = 32; off > 0; off >>= 1) v += __shfl_xor(v, off, 64);
  return v;
}

// Monotone float->uint mapping: a<b (float) <=> fenc(a)<fenc(b) (uint)
__device__ __forceinline__ unsigned int fenc(float f) {
  unsigned int u = __float_as_uint(f);
  return (u & 0x80000000u) ? ~u : (u | 0x80000000u);
}

// byte address of fp16 element (row,k) in a [rows][32] fp16 tile (64 B rows),
// XOR-swizzled so 16-lane column reads spread across all 32 banks (T2).
__device__ __forceinline__ int swz(int row, int k) {
  return (row * 64 + k * 2) ^ ((row & 7) << 4);
}

// ---------------- init: e2, r2, keys, lossCell ----------------
__global__ __launch_bounds__(256) void rvq_init_kernel(
    const float* __restrict__ x, const float* __restrict__ cb,
    float* __restrict__ e2, float* __restrict__ r2,
    unsigned long long* __restrict__ keys, float* __restrict__ lossCell) {
  if (blockIdx.x == 0 && threadIdx.x == 0) *lossCell = 0.f;
  for (int i = blockIdx.x * 256 + threadIdx.x; i < M_TOK; i += gridDim.x * 256)
    keys[i] = ~0ull;
  int row = blockIdx.x * 4 + (threadIdx.x >> 6);
  int lane = threadIdx.x & 63;
  const float* src;
  float* dst;
  if (row < NQ * KCB) {
    src = cb + (size_t)row * DIM;
    dst = e2 + row;
  } else {
    int t = row - NQ * KCB;
    if (t >= M_TOK) return;
    src = x + (size_t)t * DIM;
    dst = r2 + t;
  }
  const float4* s4 = (const float4*)src;
  float s = 0.f;
  float4 v = s4[lane];
  s += v.x * v.x + v.y * v.y + v.z * v.z + v.w * v.w;
  v = s4[lane + 64];
  s += v.x * v.x + v.y * v.y + v.z * v.z + v.w * v.w;
  s = wave_reduce_sum(s);
  if (lane == 0) *dst = s;
}

// ---------------- pre-split all codebooks: fp32 -> (hi, lo) fp16 ----------------
__global__ __launch_bounds__(256) void rvq_split_cb_kernel(
    const float* __restrict__ cb, _Float16* __restrict__ cbh,
    _Float16* __restrict__ cbl) {
  size_t i4 = (size_t)blockIdx.x * 256 + threadIdx.x;  // float4 index
  if (i4 >= (size_t)NQ * KCB * DIM / 4) return;
  float4 v = ((const float4*)cb)[i4];
  f16x4 h, l;
  float vv[4] = {v.x, v.y, v.z, v.w};
#pragma unroll
  for (int j = 0; j < 4; ++j) {
    _Float16 hh = (_Float16)vv[j];
    h[j] = hh;
    l[j] = (_Float16)(vv[j] - (float)hh);  // a-h exact (Sterbenz), then rn
  }
  ((f16x4*)cbh)[i4] = h;
  ((f16x4*)cbl)[i4] = l;
}

// ---------------- fused distance GEMM (MFMA, split-fp16) + argmin ----------------
__global__ __launch_bounds__(256, 3) void rvq_argmin_kernel(
    const float* __restrict__ rin,        // [32000][512] fp32 residual
    const _Float16* __restrict__ cbh,     // [1024][512] hi split (this stage)
    const _Float16* __restrict__ cbl,     // [1024][512] lo split
    const float* __restrict__ e2,         // [1024]
    const float* __restrict__ r2in,       // [32000]
    unsigned long long* __restrict__ keys) {  // [32000], pre-armed ~0
  // virtual (m, n-chunk) with same-m blocks sharing bid%8 -> same XCD (T1)
  const int bid = blockIdx.x;
  const int m = (bid >> 5) * 8 + (bid & 7);
  if (m >= M_TOK / BM) return;
  const int ncl = (bid >> 3) & 3;
  const int m0 = m * BM;
  const int n0 = ncl * BN;

  __shared__ __align__(16) _Float16 sAhi[BM * BK];   // 4 KB, swizzled
  __shared__ __align__(16) _Float16 sAlo[BM * BK];
  __shared__ __align__(16) _Float16 sBhi[BN * BK];   // 16 KB, swizzled
  __shared__ __align__(16) _Float16 sBlo[BN * BK];
  __shared__ float e2s[BN];
  __shared__ float r2s[BM];

  const int tid = threadIdx.x;
  const int lane = tid & 63, wn = tid >> 6;  // 4 waves = 4 col slices of 64
  const int l15 = lane & 15, l4 = lane >> 4;

  e2s[tid] = e2[n0 + tid];
  if (tid < BM) r2s[tid] = r2in[m0 + tid];

  f32x4 acc[4][4];
#pragma unroll
  for (int a = 0; a < 4; ++a)
#pragma unroll
    for (int b = 0; b < 4; ++b) acc[a][b] = (f32x4){0.f, 0.f, 0.f, 0.f};

  for (int ks = 0; ks < KSTEPS; ++ks) {
    const int kc = ks * BK;
    __syncthreads();  // protect LDS from previous iteration's readers
    // --- stage A: fp32 -> split fp16, 2 float4 per thread ---
#pragma unroll
    for (int t = 0; t < 2; ++t) {
      int p = tid + t * 256;            // 512 float4 slots
      int row = p >> 3, kk = (p & 7) * 4;
      float4 v = *(const float4*)(rin + (size_t)(m0 + row) * DIM + kc + kk);
      float vv[4] = {v.x, v.y, v.z, v.w};
      f16x4 h, l;
#pragma unroll
      for (int j = 0; j < 4; ++j) {
        _Float16 hh = (_Float16)vv[j];
        h[j] = hh;
        l[j] = (_Float16)(vv[j] - (float)hh);
      }
      int off = swz(row, kk);
      *(f16x4*)((char*)sAhi + off) = h;
      *(f16x4*)((char*)sAlo + off) = l;
    }
    // --- stage B: copy pre-split fp16, 4 x 16B per thread per array ---
#pragma unroll
    for (int it = 0; it < 4; ++it) {
      int c = tid + it * 256;           // 1024 16B-chunks
      int r = c >> 2, slot = c & 3;
      size_t gsrc = (size_t)(n0 + r) * DIM + kc + slot * 8;
      int off = swz(r, slot * 8);
      *(uint4*)((char*)sBhi + off) = *(const uint4*)(cbh + gsrc);
      *(uint4*)((char*)sBlo + off) = *(const uint4*)(cbl + gsrc);
    }
    __syncthreads();
    // --- compute: 16 ds_read_b128, 48 MFMA ---
    f16x8 ah[4], al[4];
#pragma unroll
    for (int mf = 0; mf < 4; ++mf) {
      int off = swz(mf * 16 + l15, l4 * 8);
      ah[mf] = *(const f16x8*)((const char*)sAhi + off);
      al[mf] = *(const f16x8*)((const char*)sAlo + off);
    }
#pragma unroll
    for (int nf = 0; nf < 4; ++nf) {
      int off = swz(wn * 64 + nf * 16 + l15, l4 * 8);
      f16x8 bh = *(const f16x8*)((const char*)sBhi + off);
      f16x8 bl = *(const f16x8*)((const char*)sBlo + off);
#pragma unroll
      for (int mf = 0; mf < 4; ++mf) {
        acc[mf][nf] = __builtin_amdgcn_mfma_f32_16x16x32_f16(ah[mf], bh, acc[mf][nf], 0, 0, 0);
        acc[mf][nf] = __builtin_amdgcn_mfma_f32_16x16x32_f16(ah[mf], bl, acc[mf][nf], 0, 0, 0);
        acc[mf][nf] = __builtin_amdgcn_mfma_f32_16x16x32_f16(al[mf], bh, acc[mf][nf], 0, 0, 0);
      }
    }
  }

  // --- fold: dist = (r2 - 2*dot) + e2, block-local argmin then atomicMin ---
  float minv[16];
  int mini[16];
#pragma unroll
  for (int i = 0; i < 16; ++i) { minv[i] = 3.4e38f; mini[i] = 0; }
#pragma unroll
  for (int nf = 0; nf < 4; ++nf) {
    int col_l = wn * 64 + nf * 16 + l15;
    float e2v = e2s[col_l];
    int colg = n0 + col_l;
#pragma unroll
    for (int mf = 0; mf < 4; ++mf) {
#pragma unroll
      for (int rr = 0; rr < 4; ++rr) {
        float d = (r2s[mf * 16 + l4 * 4 + rr] - 2.f * acc[mf][nf][rr]) + e2v;
        int i = mf * 4 + rr;
        if (d < minv[i]) { minv[i] = d; mini[i] = colg; }
      }
    }
  }
#pragma unroll
  for (int mf = 0; mf < 4; ++mf) {
#pragma unroll
    for (int rr = 0; rr < 4; ++rr) {
      int i = mf * 4 + rr;
      float v = minv[i];
      int ix = mini[i];
#pragma unroll
      for (int off = 8; off; off >>= 1) {
        float ov = __shfl_xor(v, off, 16);
        int oi = __shfl_xor(ix, off, 16);
        if (ov < v || (ov == v && oi < ix)) { v = ov; ix = oi; }
      }
      if (l15 == 0) {
        int tok = m0 + mf * 16 + l4 * 4 + rr;
        unsigned long long key = ((unsigned long long)fenc(v) << 32) | (unsigned)ix;
        atomicMin(&keys[tok], key);
      }
    }
  }
}

// ---------------- per-token update: gather, straight-through, loss ----------------
// 64 tokens per block; exact reference rounding; re-arms keys for next stage.
__global__ __launch_bounds__(256) void rvq_update_kernel(
    const float* __restrict__ rin, const float* __restrict__ cb,
    unsigned long long* __restrict__ keys,
    float* __restrict__ rout, float* __restrict__ r2out,
    float* __restrict__ idx_out, float* __restrict__ lossCell) {
  const int wave = threadIdx.x >> 6, lane = threadIdx.x & 63;
  __shared__ float lred[4];
  float lpart = 0.f;
  for (int r = wave; r < 64; r += 4) {
    const int tok = blockIdx.x * 64 + r;
    const unsigned idx = (unsigned)(keys[tok] & 0xffffffffu);
    const float4* rrow = (const float4*)(rin + (size_t)tok * DIM);
    const float4* crow = (const float4*)(cb + (size_t)idx * DIM);
    float4* orow = (float4*)(rout + (size_t)tok * DIM);
    float ssq_t = 0.f, ssq_r = 0.f;
#pragma unroll
    for (int c4 = 0; c4 < 2; ++c4) {
      int c = lane + c4 * 64;
      float4 a = rrow[c], q = crow[c];
      // t = q - r; qst = r + t; r_new = r - qst; loss += t^2
      float4 t = make_float4(q.x - a.x, q.y - a.y, q.z - a.z, q.w - a.w);
      float4 qst = make_float4(a.x + t.x, a.y + t.y, a.z + t.z, a.w + t.w);
      float4 rn = make_float4(a.x - qst.x, a.y - qst.y, a.z - qst.z, a.w - qst.w);
      orow[c] = rn;
      ssq_t += t.x * t.x + t.y * t.y + t.z * t.z + t.w * t.w;
      ssq_r += rn.x * rn.x + rn.y * rn.y + rn.z * rn.z + rn.w * rn.w;
    }
    float tot_t = wave_reduce_sum(ssq_t);
    float tot_r = wave_reduce_sum(ssq_r);
    if (lane == 0) {
      idx_out[tok] = (float)idx;
      keys[tok] = ~0ull;  // re-arm for next stage
      r2out[tok] = tot_r;
      lpart += tot_t;
    }
  }
  if (lane == 0) lred[wave] = lpart;
  __syncthreads();
  if (threadIdx.x == 0)
    atomicAdd(lossCell, lred[0] + lred[1] + lred[2] + lred[3]);
}

// ---------------- finalize: out = x - r8, loss scale ----------------
__global__ __launch_bounds__(256) void rvq_finalize_kernel(
    const float* __restrict__ x, float* __restrict__ out,
    const float* __restrict__ lossCell, float* __restrict__ loss_out) {
  size_t i = (size_t)blockIdx.x * 256 + threadIdx.x;
  const size_t n4 = (size_t)M_TOK * DIM / 4;
  if (i < n4) {
    const float4* x4 = (const float4*)x;
    float4* o4 = (float4*)out;
    float4 a = x4[i], r = o4[i];
    o4[i] = make_float4(a.x - r.x, a.y - r.y, a.z - r.z, a.w - r.w);
  }
  if (blockIdx.x == 0 && threadIdx.x == 0) {
    // mean over stages of 1.25*mean_elem(t^2): 1.25 / (8 * 16384000)
    *loss_out = *lossCell * (1.25f / 131072000.f);
  }
}

extern "C" void kernel_launch(void* const* d_in, const int* in_sizes, int n_in,
                              void* d_out, int out_size, void* d_ws, size_t ws_size,
                              hipStream_t stream) {
  const float* x = (const float*)d_in[0];        // [16,2000,512]
  const float* cb = (const float*)d_in[1];       // [8,1024,512]
  float* out = (float*)d_out;                    // quantized region = residual buffer
  float* idx_out = out + (size_t)M_TOK * DIM;    // [8][32000] indices as float
  float* loss_out = idx_out + (size_t)NQ * M_TOK;

  // ws layout (bytes): keys | e2 | r2 | lossCell | cbh | cbl  (~17.2 MB)
  char* w = (char*)d_ws;
  unsigned long long* keys = (unsigned long long*)w;               // 256000
  float* e2 = (float*)(w + 256000);                                 // 32768
  float* r2 = (float*)(w + 289792);                                 // 128000
  float* lossCell = (float*)(w + 417792);                           // 16
  _Float16* cbh = (_Float16*)(w + 417808 + 240);                    // align 16
  _Float16* cbl = cbh + (size_t)NQ * KCB * DIM;

  {
    int rows = NQ * KCB + M_TOK;  // 40192
    rvq_init_kernel<<<(rows + 3) / 4, 256, 0, stream>>>(x, cb, e2, r2, keys, lossCell);
    int n4 = NQ * KCB * DIM / 4;  // 1,048,576 float4
    rvq_split_cb_kernel<<<n4 / 256, 256, 0, stream>>>(cb, cbh, cbl);
  }
  float* resbuf = out;
  const int nsuper = ((M_TOK / BM) + 7) / 8;           // 63
  for (int s = 0; s < NQ; ++s) {
    const float* rin = (s == 0) ? x : resbuf;
    const float* cbs = cb + (size_t)s * KCB * DIM;
    rvq_argmin_kernel<<<nsuper * 32, 256, 0, stream>>>(
        rin, cbh + (size_t)s * KCB * DIM, cbl + (size_t)s * KCB * DIM,
        e2 + s * KCB, r2, keys);
    rvq_update_kernel<<<M_TOK / 64, 256, 0, stream>>>(
        rin, cbs, keys, resbuf, r2, idx_out + (size_t)s * M_TOK, lossCell);
  }
  rvq_finalize_kernel<<<(M_TOK * DIM / 4 + 255) / 256, 256, 0, stream>>>(
      x, out, lossCell, loss_out);
}